// Round 6
// baseline (235.475 us; speedup 1.0000x reference)
//
#include <hip/hip_runtime.h>
#include <hip/hip_cooperative_groups.h>

namespace cg = cooperative_groups;

typedef __attribute__((ext_vector_type(8))) short bf16x8;
typedef __attribute__((ext_vector_type(4))) float f32x4;
typedef __attribute__((ext_vector_type(4))) float f4v;
typedef __attribute__((ext_vector_type(4))) unsigned short u16x4;

#define NB 16
#define NC 128
#define NN 16384

__device__ __forceinline__ unsigned int f2bf_pack(float lo, float hi) {
  unsigned int ulo = __float_as_uint(lo);
  unsigned int uhi = __float_as_uint(hi);
  ulo = (ulo + 0x7FFFu + ((ulo >> 16) & 1u)) >> 16;
  uhi = (uhi + 0x7FFFu + ((uhi >> 16) & 1u)) & 0xFFFF0000u;
  return ulo | uhi;
}

__device__ __forceinline__ unsigned short f2bf_one(float v) {
  unsigned int u = __float_as_uint(v);
  return (unsigned short)((u + 0x7FFFu + ((u >> 16) & 1u)) >> 16);
}

__device__ __forceinline__ float bf2f(unsigned int u16) {
  return __uint_as_float(u16 << 16);
}

//==================== shared phase bodies (used by fused + split) ====================

#define LOADPF(PF, KS)                                                      \
  {                                                                         \
    _Pragma("unroll") for (int i = 0; i < 4; ++i) {                         \
      const float* src = xb + (size_t)srow[i] * NN + (KS)*64 + sseg[i] * 8; \
      PF[i][0] = *(const f4v*)src;                                          \
      PF[i][1] = *(const f4v*)(src + 4);                                    \
    }                                                                       \
  }

#define PACKPF(PF, BUF)                                                     \
  {                                                                         \
    _Pragma("unroll") for (int i = 0; i < 4; ++i) {                         \
      uint4 pk;                                                             \
      pk.x = f2bf_pack(PF[i][0][0], PF[i][0][1]);                           \
      pk.y = f2bf_pack(PF[i][0][2], PF[i][0][3]);                           \
      pk.z = f2bf_pack(PF[i][1][0], PF[i][1][1]);                           \
      pk.w = f2bf_pack(PF[i][1][2], PF[i][1][3]);                           \
      int byte = (srow[i] * 128 + sseg[i] * 16) ^ ((srow[i] & 7) << 4);     \
      *(uint4*)((BUF) + byte) = pk;                                         \
    }                                                                       \
  }

#define MFMAPH(BUF)                                                                          \
  {                                                                                          \
    _Pragma("unroll") for (int kh = 0; kh < 2; ++kh) {                                       \
      const int kbyte = kh * 64 + q * 16;                                                    \
      int ra = wv * 32 + l15;                                                                \
      bf16x8 a0 = *(const bf16x8*)((BUF) + ((ra * 128 + kbyte) ^ ((ra & 7) << 4)));          \
      int rb = wv * 32 + 16 + l15;                                                           \
      bf16x8 a1 = *(const bf16x8*)((BUF) + ((rb * 128 + kbyte) ^ ((rb & 7) << 4)));          \
      _Pragma("unroll") for (int ct = 0; ct < 8; ++ct) {                                     \
        int rc = ct * 16 + l15;                                                              \
        bf16x8 bb = *(const bf16x8*)((BUF) + ((rc * 128 + kbyte) ^ ((rc & 7) << 4)));        \
        acc[0][ct] = __builtin_amdgcn_mfma_f32_16x16x32_bf16(a0, bb, acc[0][ct], 0, 0, 0);   \
        acc[1][ct] = __builtin_amdgcn_mfma_f32_16x16x32_bf16(a1, bb, acc[1][ct], 0, 0, 0);   \
      }                                                                                      \
    }                                                                                        \
  }

// Phase A body: partial Gram for (b, ch) into partials[g]
__device__ __forceinline__ void phaseA_body(const float* __restrict__ x,
                                            unsigned short* __restrict__ partials,
                                            char* lds, int t, int g, int chunks, int ksteps) {
  const int b  = g / chunks;
  const int ch = g % chunks;
  const int lane = t & 63, wv = t >> 6, l15 = lane & 15, q = lane >> 4;
  const int kc = ksteps * 64;
  const float* xb = x + (size_t)b * NC * NN + (size_t)ch * kc;

  f32x4 acc[2][8];
#pragma unroll
  for (int i = 0; i < 2; ++i)
#pragma unroll
    for (int j = 0; j < 8; ++j) acc[i][j] = (f32x4){0.f, 0.f, 0.f, 0.f};

  int srow[4], sseg[4];
#pragma unroll
  for (int i = 0; i < 4; ++i) { int id = t + 256 * i; srow[i] = id >> 3; sseg[i] = id & 7; }

  f4v pfA[4][2], pfB[4][2];
  char* buf0 = lds;
  char* buf1 = lds + 16384;

  LOADPF(pfA, 0);
  PACKPF(pfA, buf0);
  if (1 < ksteps) LOADPF(pfB, 1);
  __syncthreads();

  for (int ks = 0; ks < ksteps; ks += 2) {
    if (ks + 2 < ksteps) LOADPF(pfA, ks + 2);
    MFMAPH(buf0);
    if (ks + 1 < ksteps) PACKPF(pfB, buf1);
    __syncthreads();
    if (ks + 1 < ksteps) {
      if (ks + 3 < ksteps) LOADPF(pfB, ks + 3);
      MFMAPH(buf1);
      if (ks + 2 < ksteps) PACKPF(pfA, buf0);
      __syncthreads();
    }
  }

  unsigned short* part = partials + (size_t)g * (NC * NC);
#pragma unroll
  for (int rt = 0; rt < 2; ++rt)
#pragma unroll
    for (int ct = 0; ct < 8; ++ct)
#pragma unroll
      for (int r = 0; r < 4; ++r) {
        int i = wv * 32 + rt * 16 + q * 4 + r;
        int j = ct * 16 + l15;
        part[i * 128 + j] = f2bf_one(acc[rt][ct][r]);
      }
}

// Phase B unit: reduce 4 gram rows (b, d0..d0+3) + M-columns via symmetry
__device__ __forceinline__ void phaseB_unit(const unsigned short* __restrict__ partials,
                                            const float* __restrict__ w,
                                            unsigned short* __restrict__ Mbf,
                                            float* glds, int t, int u, int chunks) {
  const int b  = u >> 5;
  const int d0 = (u & 31) * 4;

  const int rr = t >> 6;
  const int c2 = (t & 63) * 2;
  const unsigned short* pb =
      partials + (size_t)b * chunks * (NC * NC) + (d0 + rr) * 128 + c2;
  float s0 = 0.f, s1 = 0.f;
  for (int chn = 0; chn < chunks; ++chn) {
    unsigned int v = *(const unsigned int*)(pb + (size_t)chn * (NC * NC));
    s0 += bf2f(v & 0xFFFFu);
    s1 += bf2f(v >> 16);
  }
  s0 *= (1.0f / 16384.0f);
  s1 *= (1.0f / 16384.0f);
  glds[rr * 128 + c2] = s0;
  glds[rr * 128 + c2 + 1] = s1;
  __syncthreads();

  const int o  = t & 127;
  const int j0 = (t >> 7) * 2;
  float m0 = 0.f, m1 = 0.f;
  for (int c = 0; c < 128; c += 4) {
    f4v wr = *(const f4v*)(w + o * 128 + c);
    f4v ga = *(const f4v*)(glds + (j0 + 0) * 128 + c);
    f4v gb = *(const f4v*)(glds + (j0 + 1) * 128 + c);
    m0 = fmaf(wr[0], ga[0], m0); m0 = fmaf(wr[1], ga[1], m0);
    m0 = fmaf(wr[2], ga[2], m0); m0 = fmaf(wr[3], ga[3], m0);
    m1 = fmaf(wr[0], gb[0], m1); m1 = fmaf(wr[1], gb[1], m1);
    m1 = fmaf(wr[2], gb[2], m1); m1 = fmaf(wr[3], gb[3], m1);
  }
  *(unsigned int*)(Mbf + (size_t)b * NC * NC + o * 128 + d0 + j0) = f2bf_pack(m0, m1);
  __syncthreads();
}

// Phase C tile: out[b, :, n0:n0+128] = M[b] @ X[b, :, n0:n0+128]
__device__ __forceinline__ void phaseC_tile(const float* __restrict__ x,
                                            const bf16x8 afr[2][4],
                                            float* __restrict__ out,
                                            char* lds, int t, int b, int n0) {
  const int lane = t & 63, wv = t >> 6, l15 = lane & 15, q = lane >> 4;
  const float* xb = x + (size_t)b * NC * NN + n0;

#pragma unroll
  for (int i = 0; i < 2; ++i) {
    int id = t + 256 * i;
    int nb = id & 31, cb = id >> 5;
    const float* src = xb + (size_t)(cb * 8) * NN + nb * 4;
    f4v v[8];
#pragma unroll
    for (int r = 0; r < 8; ++r) v[r] = *(const f4v*)(src + (size_t)r * NN);
#pragma unroll
    for (int j = 0; j < 4; ++j) {
      int n = nb * 4 + j;
      uint4 pk;
      pk.x = f2bf_pack(v[0][j], v[1][j]);
      pk.y = f2bf_pack(v[2][j], v[3][j]);
      pk.z = f2bf_pack(v[4][j], v[5][j]);
      pk.w = f2bf_pack(v[6][j], v[7][j]);
      int byte = (n * 256 + cb * 16) ^ ((((n & 7) ^ ((n >> 3) & 7))) << 4);
      *(uint4*)(lds + byte) = pk;
    }
  }
  __syncthreads();

  f32x4 acc[2][8];
#pragma unroll
  for (int i = 0; i < 2; ++i)
#pragma unroll
    for (int j = 0; j < 8; ++j) acc[i][j] = (f32x4){0.f, 0.f, 0.f, 0.f};

#pragma unroll
  for (int ks = 0; ks < 4; ++ks) {
#pragma unroll
    for (int ct = 0; ct < 8; ++ct) {
      int n = ct * 16 + l15;
      int byte = (n * 256 + ks * 64 + q * 16) ^ ((((n & 7) ^ ((n >> 3) & 7))) << 4);
      bf16x8 bfr = *(const bf16x8*)(lds + byte);
      acc[0][ct] = __builtin_amdgcn_mfma_f32_16x16x32_bf16(afr[0][ks], bfr, acc[0][ct], 0, 0, 0);
      acc[1][ct] = __builtin_amdgcn_mfma_f32_16x16x32_bf16(afr[1][ks], bfr, acc[1][ct], 0, 0, 0);
    }
  }

  float* ob = out + (size_t)b * NC * NN + n0;
#pragma unroll
  for (int rt = 0; rt < 2; ++rt)
#pragma unroll
    for (int ct = 0; ct < 8; ++ct)
#pragma unroll
      for (int r = 0; r < 4; ++r) {
        int o = wv * 32 + rt * 16 + q * 4 + r;
        int n = ct * 16 + l15;
        ob[(size_t)o * NN + n] = acc[rt][ct][r];
      }
  __syncthreads();
}

__device__ __forceinline__ void loadM(const unsigned short* __restrict__ Mbf,
                                      bf16x8 afr[2][4], int t, int b) {
  const int lane = t & 63, wv = t >> 6, l15 = lane & 15, q = lane >> 4;
  const unsigned short* mb = Mbf + (size_t)b * NC * NC;
#pragma unroll
  for (int rt = 0; rt < 2; ++rt)
#pragma unroll
    for (int ks = 0; ks < 4; ++ks) {
      int o = wv * 32 + rt * 16 + l15;
      afr[rt][ks] = *(const bf16x8*)(mb + o * 128 + ks * 32 + q * 8);
    }
}

//==================== fused cooperative kernel ====================
__global__ __launch_bounds__(256, 2)
void nlm_fused_kernel(const float* __restrict__ x, const float* __restrict__ w,
                      float* __restrict__ out, unsigned short* __restrict__ partials,
                      unsigned short* __restrict__ Mbf, int chunks, int ksteps) {
  __shared__ __align__(16) char lds[32768];
  const int t = threadIdx.x;
  const int g = blockIdx.x;
  cg::grid_group grid = cg::this_grid();

  phaseA_body(x, partials, lds, t, g, chunks, ksteps);

  __threadfence();
  grid.sync();

  for (int u = g; u < NB * 32; u += gridDim.x)
    phaseB_unit(partials, w, Mbf, (float*)lds, t, u, chunks);

  __threadfence();
  grid.sync();

  {
    const int tiles_per = (NB * 128) / gridDim.x;
    const int tile0 = g * tiles_per;
    const int b = tile0 >> 7;
    bf16x8 afr[2][4];
    loadM(Mbf, afr, t, b);
    for (int it = 0; it < tiles_per; ++it) {
      const int tile = tile0 + it;
      phaseC_tile(x, afr, out, lds, t, b, (tile & 127) * 128);
    }
  }
}

//==================== split fallback kernels (r4-proven path) ====================
__global__ __launch_bounds__(256, 2)
void nlm_gram_kernel(const float* __restrict__ x, unsigned short* __restrict__ partials,
                     int chunks, int ksteps) {
  __shared__ __align__(16) char lds[32768];
  phaseA_body(x, partials, lds, threadIdx.x, blockIdx.x, chunks, ksteps);
}

__global__ __launch_bounds__(256)
void nlm_gramw_kernel(const unsigned short* __restrict__ partials, const float* __restrict__ w,
                      unsigned short* __restrict__ Mbf, int chunks) {
  __shared__ __align__(16) float glds[4 * 128];
  phaseB_unit(partials, w, Mbf, glds, threadIdx.x, blockIdx.x, chunks);
}

__global__ __launch_bounds__(256, 2)
void nlm_out_kernel(const float* __restrict__ x, const unsigned short* __restrict__ Mbf,
                    float* __restrict__ out) {
  __shared__ __align__(16) char lds[32768];
  const int t = threadIdx.x;
  const int b = blockIdx.x >> 7;
  const int n0 = (blockIdx.x & 127) * 128;
  bf16x8 afr[2][4];
  loadM(Mbf, afr, t, b);
  phaseC_tile(x, afr, out, lds, t, b, n0);
}

extern "C" void kernel_launch(void* const* d_in, const int* in_sizes, int n_in,
                              void* d_out, int out_size, void* d_ws, size_t ws_size,
                              hipStream_t stream) {
  const float* x = (const float*)d_in[0];
  const float* w = (const float*)d_in[1];
  float* out = (float*)d_out;

  // Size the cooperative grid from the runtime's own occupancy calc (deterministic
  // device query, capture-safe). 2 blocks/CU -> 512; degraded occupancy -> 256.
  int maxB = 0;
  (void)hipOccupancyMaxActiveBlocksPerMultiprocessor(
      &maxB, (const void*)nlm_fused_kernel, 256, 0);
  int blocksPerCU = (maxB >= 2) ? 2 : 1;
  int coopGrid = blocksPerCU * 256;        // 512 or 256
  int chunks = coopGrid / NB;              // 32 or 16
  // workspace clamp (512 MiB ws >> 16-32 MiB needed; keep the guard anyway)
  while (chunks > 16 &&
         (size_t)NB * chunks * NC * NC * 2 + (size_t)NB * NC * NC * 2 > ws_size) {
    chunks >>= 1;
    coopGrid = chunks * NB;
  }
  int ksteps = (NN / chunks) / 64;

  char* wsp = (char*)d_ws;
  unsigned short* partials = (unsigned short*)wsp;
  wsp += (size_t)NB * chunks * NC * NC * 2;
  unsigned short* Mbf = (unsigned short*)wsp;

  void* kargs[] = {(void*)&x, (void*)&w, (void*)&out,
                   (void*)&partials, (void*)&Mbf, (void*)&chunks, (void*)&ksteps};
  hipError_t err = hipLaunchCooperativeKernel((const void*)nlm_fused_kernel,
                                              dim3(coopGrid), dim3(256), kargs, 0, stream);
  if (err != hipSuccess) {
    // deterministic fallback: proven 3-kernel path (r4, 88.3 us)
    hipLaunchKernelGGL(nlm_gram_kernel, dim3(NB * chunks), dim3(256), 0, stream,
                       x, partials, chunks, ksteps);
    hipLaunchKernelGGL(nlm_gramw_kernel, dim3(NB * 32), dim3(256), 0, stream,
                       partials, w, Mbf, chunks);
    hipLaunchKernelGGL(nlm_out_kernel, dim3(NB * 128), dim3(256), 0, stream,
                       x, Mbf, out);
  }
}

// Round 7
// 133.436 us; speedup vs baseline: 1.7647x; 1.7647x over previous
//
#include <hip/hip_runtime.h>

typedef __attribute__((ext_vector_type(8))) short bf16x8;
typedef __attribute__((ext_vector_type(4))) float f32x4;
typedef __attribute__((ext_vector_type(4))) float f4v;

#define NB 16
#define NC 128
#define NN 16384
#define CHUNKS 64
#define KSTEPS 4

__device__ __forceinline__ unsigned int f2bf_pack(float lo, float hi) {
  unsigned int ulo = __float_as_uint(lo);
  unsigned int uhi = __float_as_uint(hi);
  ulo = (ulo + 0x7FFFu + ((ulo >> 16) & 1u)) >> 16;
  uhi = (uhi + 0x7FFFu + ((uhi >> 16) & 1u)) & 0xFFFF0000u;
  return ulo | uhi;
}

__device__ __forceinline__ unsigned short f2bf_one(float v) {
  unsigned int u = __float_as_uint(v);
  return (unsigned short)((u + 0x7FFFu + ((u >> 16) & 1u)) >> 16);
}

__device__ __forceinline__ float bf2f(unsigned int u16) {
  return __uint_as_float(u16 << 16);
}

//==================== Kernel A: partial Gram per (batch, K-chunk) ====================
// grid = NB*CHUNKS = 1024 blocks; 3 blocks/CU resident (launch_bounds(256,3)),
// 2-deep register prefetch ping-pong (compile-time indexed).
__global__ __launch_bounds__(256, 3)
void nlm_gram_kernel(const float* __restrict__ x, unsigned short* __restrict__ partials) {
  __shared__ __align__(16) char lds[2 * 128 * 64 * 2];
  const int t = threadIdx.x;
  const int g = blockIdx.x;
  const int b  = g / CHUNKS;
  const int ch = g % CHUNKS;
  const int lane = t & 63, wv = t >> 6, l15 = lane & 15, q = lane >> 4;
  const float* xb = x + (size_t)b * NC * NN + (size_t)ch * (KSTEPS * 64);

  f32x4 acc[2][8];
#pragma unroll
  for (int i = 0; i < 2; ++i)
#pragma unroll
    for (int j = 0; j < 8; ++j) acc[i][j] = (f32x4){0.f, 0.f, 0.f, 0.f};

  int srow[4], sseg[4];
#pragma unroll
  for (int i = 0; i < 4; ++i) { int id = t + 256 * i; srow[i] = id >> 3; sseg[i] = id & 7; }

  f4v pfA[4][2], pfB[4][2];

#define LOADPF(PF, KS)                                                      \
  {                                                                         \
    _Pragma("unroll") for (int i = 0; i < 4; ++i) {                         \
      const float* src = xb + (size_t)srow[i] * NN + (KS)*64 + sseg[i] * 8; \
      PF[i][0] = *(const f4v*)src;                                          \
      PF[i][1] = *(const f4v*)(src + 4);                                    \
    }                                                                       \
  }

#define PACKPF(PF, BUF)                                                     \
  {                                                                         \
    _Pragma("unroll") for (int i = 0; i < 4; ++i) {                         \
      uint4 pk;                                                             \
      pk.x = f2bf_pack(PF[i][0][0], PF[i][0][1]);                           \
      pk.y = f2bf_pack(PF[i][0][2], PF[i][0][3]);                           \
      pk.z = f2bf_pack(PF[i][1][0], PF[i][1][1]);                           \
      pk.w = f2bf_pack(PF[i][1][2], PF[i][1][3]);                           \
      int byte = (srow[i] * 128 + sseg[i] * 16) ^ ((srow[i] & 7) << 4);     \
      *(uint4*)((BUF) + byte) = pk;                                         \
    }                                                                       \
  }

#define MFMAPH(BUF)                                                                          \
  {                                                                                          \
    _Pragma("unroll") for (int kh = 0; kh < 2; ++kh) {                                       \
      const int kbyte = kh * 64 + q * 16;                                                    \
      int ra = wv * 32 + l15;                                                                \
      bf16x8 a0 = *(const bf16x8*)((BUF) + ((ra * 128 + kbyte) ^ ((ra & 7) << 4)));          \
      int rb = wv * 32 + 16 + l15;                                                           \
      bf16x8 a1 = *(const bf16x8*)((BUF) + ((rb * 128 + kbyte) ^ ((rb & 7) << 4)));          \
      _Pragma("unroll") for (int ct = 0; ct < 8; ++ct) {                                     \
        int rc = ct * 16 + l15;                                                              \
        bf16x8 bb = *(const bf16x8*)((BUF) + ((rc * 128 + kbyte) ^ ((rc & 7) << 4)));        \
        acc[0][ct] = __builtin_amdgcn_mfma_f32_16x16x32_bf16(a0, bb, acc[0][ct], 0, 0, 0);   \
        acc[1][ct] = __builtin_amdgcn_mfma_f32_16x16x32_bf16(a1, bb, acc[1][ct], 0, 0, 0);   \
      }                                                                                      \
    }                                                                                        \
  }

  char* buf0 = lds;
  char* buf1 = lds + 16384;

  LOADPF(pfA, 0);
  PACKPF(pfA, buf0);
  LOADPF(pfB, 1);
  __syncthreads();

#pragma unroll 1
  for (int ks = 0; ks < KSTEPS; ks += 2) {
    if (ks + 2 < KSTEPS) LOADPF(pfA, ks + 2);
    MFMAPH(buf0);
    if (ks + 1 < KSTEPS) PACKPF(pfB, buf1);
    __syncthreads();
    if (ks + 1 < KSTEPS) {
      if (ks + 3 < KSTEPS) LOADPF(pfB, ks + 3);
      MFMAPH(buf1);
      if (ks + 2 < KSTEPS) PACKPF(pfA, buf0);
      __syncthreads();
    }
  }

  // C/D layout: col = lane&15, row = (lane>>4)*4 + reg
  unsigned short* part = partials + (size_t)g * (NC * NC);
#pragma unroll
  for (int rt = 0; rt < 2; ++rt)
#pragma unroll
    for (int ct = 0; ct < 8; ++ct)
#pragma unroll
      for (int r = 0; r < 4; ++r) {
        int i = wv * 32 + rt * 16 + q * 4 + r;
        int j = ct * 16 + l15;
        part[i * 128 + j] = f2bf_one(acc[rt][ct][r]);
      }
#undef LOADPF
#undef PACKPF
#undef MFMAPH
}

//==================== Kernel B: reduce + M = w @ gram (gram symmetry) ====================
// gram symmetric -> M[o,d] = dot(w[o,:], gram[d,:]). Unit = (b, 4 gram rows).
__global__ __launch_bounds__(256)
void nlm_gramw_kernel(const unsigned short* __restrict__ partials, const float* __restrict__ w,
                      unsigned short* __restrict__ Mbf) {
  __shared__ __align__(16) float glds[4 * 128];
  const int t = threadIdx.x;
  const int u = blockIdx.x;
  const int b  = u >> 5;
  const int d0 = (u & 31) * 4;

  const int rr = t >> 6;
  const int c2 = (t & 63) * 2;
  const unsigned short* pb =
      partials + (size_t)b * CHUNKS * (NC * NC) + (d0 + rr) * 128 + c2;
  float s0 = 0.f, s1 = 0.f;
  for (int chn = 0; chn < CHUNKS; ++chn) {
    unsigned int v = *(const unsigned int*)(pb + (size_t)chn * (NC * NC));
    s0 += bf2f(v & 0xFFFFu);
    s1 += bf2f(v >> 16);
  }
  s0 *= (1.0f / 16384.0f);
  s1 *= (1.0f / 16384.0f);
  glds[rr * 128 + c2] = s0;
  glds[rr * 128 + c2 + 1] = s1;
  __syncthreads();

  const int o  = t & 127;
  const int j0 = (t >> 7) * 2;
  float m0 = 0.f, m1 = 0.f;
  for (int c = 0; c < 128; c += 4) {
    f4v wr = *(const f4v*)(w + o * 128 + c);
    f4v ga = *(const f4v*)(glds + (j0 + 0) * 128 + c);
    f4v gb = *(const f4v*)(glds + (j0 + 1) * 128 + c);
    m0 = fmaf(wr[0], ga[0], m0); m0 = fmaf(wr[1], ga[1], m0);
    m0 = fmaf(wr[2], ga[2], m0); m0 = fmaf(wr[3], ga[3], m0);
    m1 = fmaf(wr[0], gb[0], m1); m1 = fmaf(wr[1], gb[1], m1);
    m1 = fmaf(wr[2], gb[2], m1); m1 = fmaf(wr[3], gb[3], m1);
  }
  *(unsigned int*)(Mbf + (size_t)b * NC * NC + o * 128 + d0 + j0) = f2bf_pack(m0, m1);
}

//==================== Kernel C: out = M @ X (128x128 tile per block) ====================
__global__ __launch_bounds__(256, 3)
void nlm_out_kernel(const float* __restrict__ x, const unsigned short* __restrict__ Mbf,
                    float* __restrict__ out) {
  __shared__ __align__(16) char lds[128 * 128 * 2];
  const int t = threadIdx.x;
  const int b = blockIdx.x >> 7;
  const int n0 = (blockIdx.x & 127) * 128;
  const int lane = t & 63, wv = t >> 6, l15 = lane & 15, q = lane >> 4;

  bf16x8 afr[2][4];
  const unsigned short* mb = Mbf + (size_t)b * NC * NC;
#pragma unroll
  for (int rt = 0; rt < 2; ++rt)
#pragma unroll
    for (int ks = 0; ks < 4; ++ks) {
      int o = wv * 32 + rt * 16 + l15;
      afr[rt][ks] = *(const bf16x8*)(mb + o * 128 + ks * 32 + q * 8);
    }

  const float* xb = x + (size_t)b * NC * NN + n0;
#pragma unroll
  for (int i = 0; i < 2; ++i) {
    int id = t + 256 * i;
    int nb = id & 31, cb = id >> 5;
    const float* src = xb + (size_t)(cb * 8) * NN + nb * 4;
    f4v v[8];
#pragma unroll
    for (int r = 0; r < 8; ++r) v[r] = *(const f4v*)(src + (size_t)r * NN);
#pragma unroll
    for (int j = 0; j < 4; ++j) {
      int n = nb * 4 + j;
      uint4 pk;
      pk.x = f2bf_pack(v[0][j], v[1][j]);
      pk.y = f2bf_pack(v[2][j], v[3][j]);
      pk.z = f2bf_pack(v[4][j], v[5][j]);
      pk.w = f2bf_pack(v[6][j], v[7][j]);
      int byte = (n * 256 + cb * 16) ^ ((((n & 7) ^ ((n >> 3) & 7))) << 4);
      *(uint4*)(lds + byte) = pk;
    }
  }
  __syncthreads();

  f32x4 acc[2][8];
#pragma unroll
  for (int i = 0; i < 2; ++i)
#pragma unroll
    for (int j = 0; j < 8; ++j) acc[i][j] = (f32x4){0.f, 0.f, 0.f, 0.f};

#pragma unroll
  for (int ks = 0; ks < 4; ++ks) {
#pragma unroll
    for (int ct = 0; ct < 8; ++ct) {
      int n = ct * 16 + l15;
      int byte = (n * 256 + ks * 64 + q * 16) ^ ((((n & 7) ^ ((n >> 3) & 7))) << 4);
      bf16x8 bfr = *(const bf16x8*)(lds + byte);
      acc[0][ct] = __builtin_amdgcn_mfma_f32_16x16x32_bf16(afr[0][ks], bfr, acc[0][ct], 0, 0, 0);
      acc[1][ct] = __builtin_amdgcn_mfma_f32_16x16x32_bf16(afr[1][ks], bfr, acc[1][ct], 0, 0, 0);
    }
  }

  float* ob = out + (size_t)b * NC * NN + n0;
#pragma unroll
  for (int rt = 0; rt < 2; ++rt)
#pragma unroll
    for (int ct = 0; ct < 8; ++ct)
#pragma unroll
      for (int r = 0; r < 4; ++r) {
        int o = wv * 32 + rt * 16 + q * 4 + r;
        int n = ct * 16 + l15;
        ob[(size_t)o * NN + n] = acc[rt][ct][r];
      }
}

extern "C" void kernel_launch(void* const* d_in, const int* in_sizes, int n_in,
                              void* d_out, int out_size, void* d_ws, size_t ws_size,
                              hipStream_t stream) {
  const float* x = (const float*)d_in[0];
  const float* w = (const float*)d_in[1];
  float* out = (float*)d_out;

  char* wsp = (char*)d_ws;
  unsigned short* partials = (unsigned short*)wsp;              // 32 MiB (bf16)
  wsp += (size_t)NB * CHUNKS * NC * NC * 2;
  unsigned short* Mbf = (unsigned short*)wsp;                   // 512 KiB

  hipLaunchKernelGGL(nlm_gram_kernel, dim3(NB * CHUNKS), dim3(256), 0, stream,
                     x, partials);
  hipLaunchKernelGGL(nlm_gramw_kernel, dim3(NB * 32), dim3(256), 0, stream,
                     partials, w, Mbf);
  hipLaunchKernelGGL(nlm_out_kernel, dim3(NB * 128), dim3(256), 0, stream,
                     x, Mbf, out);
}

// Round 9
// 107.858 us; speedup vs baseline: 2.1832x; 1.2371x over previous
//
#include <hip/hip_runtime.h>

typedef __attribute__((ext_vector_type(8))) short bf16x8;
typedef __attribute__((ext_vector_type(4))) float f32x4;
typedef __attribute__((ext_vector_type(4))) float f4v;

#define NB 16
#define NC 128
#define NN 16384
#define CHUNKS 64
#define KC 256  // cols per chunk slab

__device__ __forceinline__ unsigned int f2bf_pack(float lo, float hi) {
  unsigned int ulo = __float_as_uint(lo);
  unsigned int uhi = __float_as_uint(hi);
  ulo = (ulo + 0x7FFFu + ((ulo >> 16) & 1u)) >> 16;
  uhi = (uhi + 0x7FFFu + ((uhi >> 16) & 1u)) & 0xFFFF0000u;
  return ulo | uhi;
}

__device__ __forceinline__ unsigned short f2bf_one(float v) {
  unsigned int u = __float_as_uint(v);
  return (unsigned short)((u + 0x7FFFu + ((u >> 16) & 1u)) >> 16);
}

__device__ __forceinline__ float bf2f(unsigned int u16) {
  return __uint_as_float(u16 << 16);
}

//==================== Kernel A: partial Gram, slab-per-block ====================
// Block (b, ch) owns x[b, :, ch*256:(ch+1)*256]. Load whole slab into one
// 64-KiB swizzled LDS buffer with per-instruction 1-KiB single-row runs
// (DRAM-friendly + coalesced), ONE barrier, then a pure-MFMA phase (8 K-slices,
// no barriers), then a coalesced full-line epilogue through LDS.
__global__ __launch_bounds__(256, 2)
void nlm_gram_kernel(const float* __restrict__ x, unsigned short* __restrict__ partials) {
  __shared__ __align__(16) char lds[128 * KC * 2];  // 64 KiB
  const int t = threadIdx.x;
  const int g = blockIdx.x;
  const int b  = g >> 6;
  const int ch = g & 63;
  const int lane = t & 63, wv = t >> 6, l15 = lane & 15, q = lane >> 4;

  const float* xb = x + (size_t)b * NC * NN + (size_t)ch * KC;

  // ---- load phase: wave wv loads rows [wv*32, wv*32+32); lane l -> cols [4l,4l+4)
  // (128 rows x 64 lane-tasks = 32 iters/thread; r8 bug was 16 -> half slab stale)
#pragma unroll
  for (int j = 0; j < 32; ++j) {
    const int row = wv * 32 + j;
    f4v v = *(const f4v*)(xb + (size_t)row * NN + 4 * lane);
    uint2 pk;
    pk.x = f2bf_pack(v[0], v[1]);
    pk.y = f2bf_pack(v[2], v[3]);
    int byte = (row * (KC * 2) + lane * 8) ^ ((row & 7) << 4);
    *(uint2*)(lds + byte) = pk;
  }
  __syncthreads();

  // ---- MFMA phase: 8 K-slices of 32, no barriers
  f32x4 acc[2][8];
#pragma unroll
  for (int i = 0; i < 2; ++i)
#pragma unroll
    for (int j = 0; j < 8; ++j) acc[i][j] = (f32x4){0.f, 0.f, 0.f, 0.f};

#pragma unroll
  for (int ks = 0; ks < 8; ++ks) {
    const int kbyte = ks * 64 + q * 16;
    int ra = wv * 32 + l15;
    bf16x8 a0 = *(const bf16x8*)(lds + ((ra * (KC * 2) + kbyte) ^ ((ra & 7) << 4)));
    int rb = wv * 32 + 16 + l15;
    bf16x8 a1 = *(const bf16x8*)(lds + ((rb * (KC * 2) + kbyte) ^ ((rb & 7) << 4)));
#pragma unroll
    for (int ct = 0; ct < 8; ++ct) {
      int rc = ct * 16 + l15;
      bf16x8 bb = *(const bf16x8*)(lds + ((rc * (KC * 2) + kbyte) ^ ((rc & 7) << 4)));
      acc[0][ct] = __builtin_amdgcn_mfma_f32_16x16x32_bf16(a0, bb, acc[0][ct], 0, 0, 0);
      acc[1][ct] = __builtin_amdgcn_mfma_f32_16x16x32_bf16(a1, bb, acc[1][ct], 0, 0, 0);
    }
  }
  __syncthreads();  // slab consumed; reuse LDS for output staging

  // ---- epilogue: stage 128x128 bf16 tile in LDS, then full-line linear stores
  unsigned short* lds16 = (unsigned short*)lds;
#pragma unroll
  for (int rt = 0; rt < 2; ++rt)
#pragma unroll
    for (int ct = 0; ct < 8; ++ct)
#pragma unroll
      for (int r = 0; r < 4; ++r) {
        int i = wv * 32 + rt * 16 + q * 4 + r;  // C/D layout: col=lane&15, row=(lane>>4)*4+reg
        int j = ct * 16 + l15;
        lds16[i * 128 + j] = f2bf_one(acc[rt][ct][r]);
      }
  __syncthreads();

  unsigned short* part = partials + (size_t)g * (NC * NC);
#pragma unroll
  for (int ii = 0; ii < 8; ++ii) {
    int off = ii * 4096 + t * 16;  // bytes
    *(uint4*)((char*)part + off) = *(const uint4*)(lds + off);
  }
}

//==================== Kernel B: reduce + M = w @ gram (gram symmetry) ====================
// gram symmetric -> M[o,d] = dot(w[o,:], gram[d,:]). Unit = (b, 4 gram rows).
__global__ __launch_bounds__(256)
void nlm_gramw_kernel(const unsigned short* __restrict__ partials, const float* __restrict__ w,
                      unsigned short* __restrict__ Mbf) {
  __shared__ __align__(16) float glds[4 * 128];
  const int t = threadIdx.x;
  const int u = blockIdx.x;
  const int b  = u >> 5;
  const int d0 = (u & 31) * 4;

  const int rr = t >> 6;
  const int c2 = (t & 63) * 2;
  const unsigned short* pb =
      partials + (size_t)b * CHUNKS * (NC * NC) + (d0 + rr) * 128 + c2;
  float s0 = 0.f, s1 = 0.f;
  for (int chn = 0; chn < CHUNKS; ++chn) {
    unsigned int v = *(const unsigned int*)(pb + (size_t)chn * (NC * NC));
    s0 += bf2f(v & 0xFFFFu);
    s1 += bf2f(v >> 16);
  }
  s0 *= (1.0f / 16384.0f);
  s1 *= (1.0f / 16384.0f);
  glds[rr * 128 + c2] = s0;
  glds[rr * 128 + c2 + 1] = s1;
  __syncthreads();

  const int o  = t & 127;
  const int j0 = (t >> 7) * 2;
  float m0 = 0.f, m1 = 0.f;
  for (int c = 0; c < 128; c += 4) {
    f4v wr = *(const f4v*)(w + o * 128 + c);
    f4v ga = *(const f4v*)(glds + (j0 + 0) * 128 + c);
    f4v gb = *(const f4v*)(glds + (j0 + 1) * 128 + c);
    m0 = fmaf(wr[0], ga[0], m0); m0 = fmaf(wr[1], ga[1], m0);
    m0 = fmaf(wr[2], ga[2], m0); m0 = fmaf(wr[3], ga[3], m0);
    m1 = fmaf(wr[0], gb[0], m1); m1 = fmaf(wr[1], gb[1], m1);
    m1 = fmaf(wr[2], gb[2], m1); m1 = fmaf(wr[3], gb[3], m1);
  }
  *(unsigned int*)(Mbf + (size_t)b * NC * NC + o * 128 + d0 + j0) = f2bf_pack(m0, m1);
}

//==================== Kernel C: out = M @ X (128x128 tile per block) ====================
__global__ __launch_bounds__(256, 2)
void nlm_out_kernel(const float* __restrict__ x, const unsigned short* __restrict__ Mbf,
                    float* __restrict__ out) {
  __shared__ __align__(16) char lds[128 * 128 * 2];
  const int t = threadIdx.x;
  const int b = blockIdx.x >> 7;
  const int n0 = (blockIdx.x & 127) * 128;
  const int lane = t & 63, wv = t >> 6, l15 = lane & 15, q = lane >> 4;

  bf16x8 afr[2][4];
  const unsigned short* mb = Mbf + (size_t)b * NC * NC;
#pragma unroll
  for (int rt = 0; rt < 2; ++rt)
#pragma unroll
    for (int ks = 0; ks < 4; ++ks) {
      int o = wv * 32 + rt * 16 + l15;
      afr[rt][ks] = *(const bf16x8*)(mb + o * 128 + ks * 32 + q * 8);
    }

  const float* xb = x + (size_t)b * NC * NN + n0;
#pragma unroll
  for (int i = 0; i < 2; ++i) {
    int id = t + 256 * i;
    int nb = id & 31, cb = id >> 5;
    const float* src = xb + (size_t)(cb * 8) * NN + nb * 4;
    f4v v[8];
#pragma unroll
    for (int r = 0; r < 8; ++r) v[r] = *(const f4v*)(src + (size_t)r * NN);
#pragma unroll
    for (int j = 0; j < 4; ++j) {
      int n = nb * 4 + j;
      uint4 pk;
      pk.x = f2bf_pack(v[0][j], v[1][j]);
      pk.y = f2bf_pack(v[2][j], v[3][j]);
      pk.z = f2bf_pack(v[4][j], v[5][j]);
      pk.w = f2bf_pack(v[6][j], v[7][j]);
      int byte = (n * 256 + cb * 16) ^ ((((n & 7) ^ ((n >> 3) & 7))) << 4);
      *(uint4*)(lds + byte) = pk;
    }
  }
  __syncthreads();

  f32x4 acc[2][8];
#pragma unroll
  for (int i = 0; i < 2; ++i)
#pragma unroll
    for (int j = 0; j < 8; ++j) acc[i][j] = (f32x4){0.f, 0.f, 0.f, 0.f};

#pragma unroll
  for (int ks = 0; ks < 4; ++ks) {
#pragma unroll
    for (int ct = 0; ct < 8; ++ct) {
      int n = ct * 16 + l15;
      int byte = (n * 256 + ks * 64 + q * 16) ^ ((((n & 7) ^ ((n >> 3) & 7))) << 4);
      bf16x8 bfr = *(const bf16x8*)(lds + byte);
      acc[0][ct] = __builtin_amdgcn_mfma_f32_16x16x32_bf16(afr[0][ks], bfr, acc[0][ct], 0, 0, 0);
      acc[1][ct] = __builtin_amdgcn_mfma_f32_16x16x32_bf16(afr[1][ks], bfr, acc[1][ct], 0, 0, 0);
    }
  }

  float* ob = out + (size_t)b * NC * NN + n0;
#pragma unroll
  for (int rt = 0; rt < 2; ++rt)
#pragma unroll
    for (int ct = 0; ct < 8; ++ct)
#pragma unroll
      for (int r = 0; r < 4; ++r) {
        int o = wv * 32 + rt * 16 + q * 4 + r;
        int n = ct * 16 + l15;
        ob[(size_t)o * NN + n] = acc[rt][ct][r];
      }
}

extern "C" void kernel_launch(void* const* d_in, const int* in_sizes, int n_in,
                              void* d_out, int out_size, void* d_ws, size_t ws_size,
                              hipStream_t stream) {
  const float* x = (const float*)d_in[0];
  const float* w = (const float*)d_in[1];
  float* out = (float*)d_out;

  char* wsp = (char*)d_ws;
  unsigned short* partials = (unsigned short*)wsp;              // 32 MiB (bf16)
  wsp += (size_t)NB * CHUNKS * NC * NC * 2;
  unsigned short* Mbf = (unsigned short*)wsp;                   // 512 KiB

  hipLaunchKernelGGL(nlm_gram_kernel, dim3(NB * CHUNKS), dim3(256), 0, stream,
                     x, partials);
  hipLaunchKernelGGL(nlm_gramw_kernel, dim3(NB * 32), dim3(256), 0, stream,
                     partials, w, Mbf);
  hipLaunchKernelGGL(nlm_out_kernel, dim3(NB * 128), dim3(256), 0, stream,
                     x, Mbf, out);
}